// Round 3
// baseline (392.369 us; speedup 1.0000x reference)
//
#include <hip/hip_runtime.h>
#include <hip/hip_bf16.h>

// EulerIntegrator: B=4096, D=1024, R=256, steps=8, dt=0.01
// R3: back to R1 structure (M=16 rows/block, grid 256, 1024 thr = 16 waves/CU,
// fp32 state regs). New: depth-8 rolling register prefetch of B-fragments in
// both GEMMs (fully unrolled, static indices), cross-barrier priming of the
// next phase's fragment loads, and raw s_barrier + lgkmcnt(0) (m201 pattern)
// instead of __syncthreads so in-flight global loads survive the barrier.
// Wave-staggered kt start spreads the post-barrier L2 burst.
// GEMM1: P[16x256] = v[16x1024] @ U   (bf16 MFMA 16x16x32)
// GEMM2: G[16x1024] = (P*P)[16x256] @ W

#define BB 4096
#define DD 1024
#define RR 256
#define DT 0.01f

typedef __attribute__((ext_vector_type(8))) short short8;   // 8 bf16 = 4 VGPRs
typedef __attribute__((ext_vector_type(4))) float floatx4;  // MFMA acc

static __device__ inline unsigned short f2bf(float f) {
    union { float f; unsigned int u; } c; c.f = f;
    unsigned int u = c.u;
    u += 0x7fffu + ((u >> 16) & 1u);   // round-to-nearest-even
    return (unsigned short)(u >> 16);
}

// Workgroup barrier WITHOUT the vmcnt(0) drain __syncthreads emits.
// LDS visibility across waves needs lgkmcnt(0) only (m201-verified pattern);
// in-flight global->VGPR prefetches stay in flight across the barrier.
static __device__ inline void lds_barrier() {
    asm volatile("s_waitcnt lgkmcnt(0)" ::: "memory");
    __builtin_amdgcn_s_barrier();
    asm volatile("" ::: "memory");
}

// Pack U [1024][256] and W [256][1024] (fp32 row-major) into bf16 MFMA
// B-fragment order: dst[(kt*NT + nt)*64 + lane] element j =
// M[kt*32 + (lane>>4)*8 + j][nt*16 + (lane&15)].
// One coalesced float4 read per thread; 4 x 2B scattered writes (tiny).
__global__ __launch_bounds__(256)
void pack_kernel(const float* __restrict__ U, const float* __restrict__ W,
                 short* __restrict__ Up, short* __restrict__ Wp) {
    int t = blockIdx.x * blockDim.x + threadIdx.x;  // 0..131071
    if (t < 65536) {
        // U: k = t>>6 (0..1023), n4 = t&63
        int k = t >> 6, n4 = t & 63;
        float4 u = *(const float4*)&U[k * RR + 4 * n4];
        int kt = k >> 5, kq = (k >> 3) & 3, j = k & 7;
        float uv[4] = {u.x, u.y, u.z, u.w};
#pragma unroll
        for (int i = 0; i < 4; i++) {
            int n = 4 * n4 + i;
            int nt = n >> 4, nl = n & 15;
            Up[(((kt * 16 + nt) * 64) + kq * 16 + nl) * 8 + j] = (short)f2bf(uv[i]);
        }
    } else {
        // W: k = 0..255, n4 = 0..255
        int t2 = t - 65536;
        int k = t2 >> 8, n4 = t2 & 255;
        float4 w = *(const float4*)&W[k * DD + 4 * n4];
        int kt = k >> 5, kq = (k >> 3) & 3, j = k & 7;
        float wv[4] = {w.x, w.y, w.z, w.w};
#pragma unroll
        for (int i = 0; i < 4; i++) {
            int n = 4 * n4 + i;
            int nt = n >> 4, nl = n & 15;
            Wp[(((kt * 64 + nt) * 64) + kq * 16 + nl) * 8 + j] = (short)f2bf(wv[i]);
        }
    }
}

__global__ __launch_bounds__(1024, 4)
void euler_kernel(const float* __restrict__ x0,
                  const float* __restrict__ v0,
                  const float* __restrict__ force,
                  const short8* __restrict__ Up,
                  const short8* __restrict__ Wp,
                  const int* __restrict__ steps_p,
                  float* __restrict__ out) {
    // LDS: bf16 v tile (padded stride 1032 -> b128 A-reads at bank floor),
    // bf16 p^2 tile (stride 264). v_lds re-aliased as f32 output stage.
    __shared__ __align__(16) short v_lds[16][1032];   // 33.0 KB
    __shared__ __align__(16) short p2_lds[16][264];   //  8.4 KB

    const int tid  = threadIdx.x;
    const int wave = tid >> 6;          // 0..15
    const int lane = tid & 63;
    const int nl   = lane & 15;         // M (A) / N (B) / col (C)
    const int quad = lane >> 4;         // 0..3
    const int row0 = blockIdx.x * 16;

    const int steps = steps_p[0];

    // Wave-staggered start tiles (spread post-barrier L2 burst)
    const int kt0  = (2 * wave) & 31;   // GEMM1 kt start
    const int kt0b = wave & 7;          // GEMM2 kt start

    // Ownership (MFMA C/D layout of GEMM2, 4 tiles/wave):
    // element (t, r): row = 4*quad + r, col = 64*wave + 16*t + nl
    float v_reg[4][4], f_reg[4][4], sv[4][4];

#pragma unroll
    for (int t = 0; t < 4; t++) {
        int col = 64 * wave + 16 * t + nl;
#pragma unroll
        for (int r = 0; r < 4; r++) {
            int row = 4 * quad + r;
            long g = (long)(row0 + row) * DD + col;
            v_reg[t][r] = v0[g];
            f_reg[t][r] = force[g];
            sv[t][r] = 0.0f;
            v_lds[row][col] = (short)f2bf(v_reg[t][r]);
        }
    }

    // Prime GEMM1 B-prefetch (depth 8) before the barrier: loads in flight
    // across it (lds_barrier does not drain vmcnt).
    short8 bq[8];
#pragma unroll
    for (int i = 0; i < 8; i++)
        bq[i] = Up[(((kt0 + i) & 31) * 16 + wave) * 64 + lane];

    lds_barrier();

    for (int s = 0; s < steps; s++) {
        // ---------------- GEMM1: P = v @ U ; wave computes nt = wave
        // Fully unrolled, rolling depth-8 prefetch (all indices static).
        floatx4 acc1 = {0.f, 0.f, 0.f, 0.f};
#pragma unroll
        for (int kk = 0; kk < 32; kk++) {
            int kt = (kt0 + kk) & 31;
            short8 a = *(const short8*)&v_lds[nl][kt * 32 + quad * 8];
            short8 b = bq[kk & 7];
            if (kk < 24)
                bq[kk & 7] = Up[(((kt0 + kk + 8) & 31) * 16 + wave) * 64 + lane];
            acc1 = __builtin_amdgcn_mfma_f32_16x16x32_bf16(a, b, acc1, 0, 0, 0);
        }

        // Prime GEMM2 B-prefetch (depth 8 of 32) before barrier A.
        short8 wq[8];
#pragma unroll
        for (int i = 0; i < 8; i++) {
            int kt = (kt0b + (i >> 2)) & 7;
            wq[i] = Wp[(kt * 64 + 4 * wave + (i & 3)) * 64 + lane];
        }

        // epilogue: p^2 -> LDS (D layout: row = 4*quad + r, col = 16*wave + nl)
#pragma unroll
        for (int r = 0; r < 4; r++) {
            float p = acc1[r];
            p2_lds[4 * quad + r][16 * wave + nl] = (short)f2bf(p * p);
        }
        lds_barrier();   // barrier A: wq loads stay in flight

        // ---------------- GEMM2: G = p2 @ W ; wave computes nt = 4w..4w+3
        floatx4 acc[4];
#pragma unroll
        for (int t = 0; t < 4; t++) acc[t] = (floatx4){0.f, 0.f, 0.f, 0.f};
#pragma unroll
        for (int kk = 0; kk < 8; kk++) {
            int kt = (kt0b + kk) & 7;
            short8 a = *(const short8*)&p2_lds[nl][kt * 32 + quad * 8];
#pragma unroll
            for (int t = 0; t < 4; t++) {
                int m = 4 * kk + t;
                short8 b = wq[m & 7];
                if (m < 24) {
                    int ktn = (kt0b + kk + 2) & 7;
                    wq[m & 7] = Wp[(ktn * 64 + 4 * wave + t) * 64 + lane];
                }
                acc[t] = __builtin_amdgcn_mfma_f32_16x16x32_bf16(a, b, acc[t], 0, 0, 0);
            }
        }

        // Prime next step's GEMM1 prefetch before barrier B (wasted on the
        // final step; addresses always valid).
#pragma unroll
        for (int i = 0; i < 8; i++)
            bq[i] = Up[(((kt0 + i) & 31) * 16 + wave) * 64 + lane];

        // epilogue: Euler update, refresh bf16 v in LDS
#pragma unroll
        for (int t = 0; t < 4; t++) {
            int col = 64 * wave + 16 * t + nl;
#pragma unroll
            for (int r = 0; r < 4; r++) {
                int row = 4 * quad + r;
                float gma = acc[t][r];
                sv[t][r] += v_reg[t][r];                       // x accumulates pre-update v
                v_reg[t][r] += DT * (f_reg[t][r] - gma);
                v_lds[row][col] = (short)f2bf(v_reg[t][r]);
            }
        }
        lds_barrier();   // barrier B: bq loads stay in flight
    }

    // ---------------- outputs: [cx | cv], cx = x0 + dt * sum(v_t)
    // Stage 8 rows at a time as f32 in the (now dead) v_lds, write coalesced
    // float4 lines; x0 read linearly as float4.
    float (*stage)[1032] = reinterpret_cast<float(*)[1032]>(&v_lds[0][0]);
    const float4* x4 = reinterpret_cast<const float4*>(x0);
    float4* out4 = reinterpret_cast<float4*>(out);

    for (int sel = 0; sel < 2; sel++) {          // 0: cx, 1: cv
        for (int half = 0; half < 2; half++) {   // rows 0..7, 8..15
            __syncthreads();
            if ((quad >> 1) == half) {
#pragma unroll
                for (int t = 0; t < 4; t++) {
                    int col = 64 * wave + 16 * t + nl;
#pragma unroll
                    for (int r = 0; r < 4; r++) {
                        int lrow = (4 * quad + r) & 7;
                        stage[lrow][col] = sel ? v_reg[t][r] : DT * sv[t][r];
                    }
                }
            }
            __syncthreads();
            // linear copy: 8 rows x 1024 cols = 2048 float4, 2 per thread
            for (int i = tid; i < 2048; i += 1024) {
                int lrow = i >> 8;               // 256 float4 per row
                int c4 = i & 255;
                long gi = (long)(row0 + half * 8 + lrow) * 256 + c4;
                float4 val = *(const float4*)&stage[lrow][c4 * 4];
                if (sel == 0) {
                    float4 xv = x4[gi];
                    val.x += xv.x; val.y += xv.y; val.z += xv.z; val.w += xv.w;
                    out4[gi] = val;
                } else {
                    out4[(long)BB * 256 + gi] = val;
                }
            }
        }
    }
}

extern "C" void kernel_launch(void* const* d_in, const int* in_sizes, int n_in,
                              void* d_out, int out_size, void* d_ws, size_t ws_size,
                              hipStream_t stream) {
    const float* x     = (const float*)d_in[0];
    const float* v     = (const float*)d_in[1];
    const float* force = (const float*)d_in[2];
    const float* U     = (const float*)d_in[3];
    const float* W     = (const float*)d_in[4];
    const int*   steps = (const int*)d_in[5];

    short* Up = (short*)d_ws;                 // 32768 * 16B = 512 KB
    short* Wp = Up + 32768 * 8;               // 512 KB

    pack_kernel<<<512, 256, 0, stream>>>(U, W, Up, Wp);
    euler_kernel<<<256, 1024, 0, stream>>>(x, v, force,
                                           (const short8*)Up, (const short8*)Wp,
                                           steps, (float*)d_out);
}

// Round 4
// 188.663 us; speedup vs baseline: 2.0797x; 2.0797x over previous
//
#include <hip/hip_runtime.h>

// EulerIntegrator: B=4096, D=1024, R=256, steps=8, dt=0.01
// R4: algorithmic restructure. P = v@U obeys a closed recurrence in [B,256]:
//   P <- P + dt*(FU - (P*P)@WU),  FU = f@U (per-block),  WU = W@U (256x256).
// The 8 per-step GEMM2s defer into two final GEMMs via weighted sums of P^2:
//   v_fin = v0 + s*dt*f - dt*(Q1@W),            Q1 = sum G_j
//   x_fin = x0 + s*dt*v0 + T*dt^2*f - dt^2*(Q2@W), Q2 = sum (s-1-j)*G_j, T = s(s-1)/2
// Per-CU L2 fragment traffic drops 8MB -> ~1.1MB; WU lives in LDS during steps.
// All GEMM fragment layouts identical to the R1-verified patterns.

#define BB 4096
#define DD 1024
#define RR 256
#define DT 0.01f

typedef __attribute__((ext_vector_type(8))) short short8;   // 8 bf16 = 4 VGPRs
typedef __attribute__((ext_vector_type(4))) short short4v;  // 4 bf16 = 8B store
typedef __attribute__((ext_vector_type(4))) float floatx4;  // MFMA acc

static __device__ inline unsigned short f2bf(float f) {
    union { float f; unsigned int u; } c; c.f = f;
    unsigned int u = c.u;
    u += 0x7fffu + ((u >> 16) & 1u);   // round-to-nearest-even
    return (unsigned short)(u >> 16);
}

// Pack U [1024][256] and W [256][1024] into bf16 MFMA B-fragment order:
// dst[(kt*NT + nt)*64 + lane] element j = M[kt*32 + (lane>>4)*8 + j][nt*16 + (lane&15)].
// Blocks 0..127: pack (1 coalesced float4 read/thread).
// Blocks 128..191: WU = W@U in fp32 (scalar dot, W-row wave-uniform, U coalesced),
// written directly into WUp B-fragment layout.
__global__ __launch_bounds__(1024)
void pack_kernel(const float* __restrict__ U, const float* __restrict__ W,
                 short* __restrict__ Up, short* __restrict__ Wp,
                 short* __restrict__ WUp) {
    int b = blockIdx.x;
    int tid = threadIdx.x;
    if (b < 128) {
        int t = b * 1024 + tid;                  // 0..131071
        if (t < 65536) {
            // U: k = t>>6 (0..1023), n4 = t&63
            int k = t >> 6, n4 = t & 63;
            float4 u = *(const float4*)&U[k * RR + 4 * n4];
            int kt = k >> 5, kq = (k >> 3) & 3, j = k & 7;
            float uv[4] = {u.x, u.y, u.z, u.w};
#pragma unroll
            for (int i = 0; i < 4; i++) {
                int n = 4 * n4 + i;
                int nt = n >> 4, nl = n & 15;
                Up[(((kt * 16 + nt) * 64) + kq * 16 + nl) * 8 + j] = (short)f2bf(uv[i]);
            }
        } else {
            // W: k = 0..255, n4 = 0..255
            int t2 = t - 65536;
            int k = t2 >> 8, n4 = t2 & 255;
            float4 w = *(const float4*)&W[k * DD + 4 * n4];
            int kt = k >> 5, kq = (k >> 3) & 3, j = k & 7;
            float wv[4] = {w.x, w.y, w.z, w.w};
#pragma unroll
            for (int i = 0; i < 4; i++) {
                int n = 4 * n4 + i;
                int nt = n >> 4, nl = n & 15;
                Wp[(((kt * 64 + nt) * 64) + kq * 16 + nl) * 8 + j] = (short)f2bf(wv[i]);
            }
        }
    } else {
        // WU[i][j] = sum_k W[i][k] * U[k][j], fp32. 64 blocks x (4 rows x 256 cols).
        int i = (b - 128) * 4 + (tid >> 8);      // 0..255 (wave-uniform)
        int j = tid & 255;
        const float* wr = W + (long)i * DD;
        float a0 = 0.f, a1 = 0.f, a2 = 0.f, a3 = 0.f;
#pragma unroll 8
        for (int k = 0; k < 1024; k += 4) {
            a0 += wr[k + 0] * U[(long)(k + 0) * RR + j];
            a1 += wr[k + 1] * U[(long)(k + 1) * RR + j];
            a2 += wr[k + 2] * U[(long)(k + 2) * RR + j];
            a3 += wr[k + 3] * U[(long)(k + 3) * RR + j];
        }
        float acc = (a0 + a1) + (a2 + a3);
        // write into WUp B-fragment layout (ktiles=8, ntiles=16)
        int kt = i >> 5, kq = (i >> 3) & 3, jj = i & 7;
        int nt = j >> 4, nl = j & 15;
        WUp[(((kt * 16 + nt) * 64) + kq * 16 + nl) * 8 + jj] = (short)f2bf(acc);
    }
}

__global__ __launch_bounds__(1024)
void euler_kernel(const float* __restrict__ x0,
                  const float* __restrict__ v0,
                  const float* __restrict__ force,
                  const short8* __restrict__ Up,
                  const short8* __restrict__ Wp,
                  const short8* __restrict__ WUp,
                  const int* __restrict__ steps_p,
                  float* __restrict__ out) {
    // LDS layout (shorts), total 73984 shorts = 147,968 B (1 block/CU):
    //   [0      .. 65535]  wu8: WU fragments (8192 short8) -- staged after init;
    //                      ALIASED during init: va [16][1032] at 0, fa at 16512;
    //                      ALIASED during epilogue: f32 stage [8][1032] (33KB).
    //   [65536  .. 69759]  p2 buf0 [16][264] (steps A dbuf / final Q1)
    //   [69760  .. 73983]  p2 buf1 [16][264] (steps A dbuf / final Q2)
    __shared__ __align__(16) short smem[73984];

    const int tid  = threadIdx.x;
    const int wave = tid >> 6;          // 0..15
    const int lane = tid & 63;
    const int nl   = lane & 15;
    const int quad = lane >> 4;
    const int row0 = blockIdx.x * 16;
    const int steps = steps_p[0];

    short (*va)[1032] = (short(*)[1032])smem;
    short (*fa)[1032] = (short(*)[1032])(smem + 16512);
    short (*q1)[264]  = (short(*)[264])(smem + 65536);
    short (*q2)[264]  = (short(*)[264])(smem + 69760);
    short8* wu8 = (short8*)smem;

    // ---- stage v0, f as bf16 (coalesced float4 reads)
    const float4* v04 = (const float4*)v0;
    const float4* f44 = (const float4*)force;
#pragma unroll
    for (int i = 0; i < 4; i++) {
        int idx = tid + i * 1024;       // 0..4095
        int row = idx >> 8, c4 = idx & 255;
        long g = (long)(row0 + row) * 256 + c4;
        float4 vv = v04[g];
        float4 ff = f44[g];
        short4v sv, sf;
        sv[0] = (short)f2bf(vv.x); sv[1] = (short)f2bf(vv.y);
        sv[2] = (short)f2bf(vv.z); sv[3] = (short)f2bf(vv.w);
        sf[0] = (short)f2bf(ff.x); sf[1] = (short)f2bf(ff.y);
        sf[2] = (short)f2bf(ff.z); sf[3] = (short)f2bf(ff.w);
        *(short4v*)&va[row][c4 * 4] = sv;
        *(short4v*)&fa[row][c4 * 4] = sf;
    }
    __syncthreads();

    // ---- init GEMMs (share B): P = v0@U, FU = f@U ; wave's nt = wave
    floatx4 P  = {0.f, 0.f, 0.f, 0.f};
    floatx4 FU = {0.f, 0.f, 0.f, 0.f};
#pragma unroll 4
    for (int kt = 0; kt < 32; kt++) {
        short8 av = *(const short8*)&va[nl][kt * 32 + quad * 8];
        short8 af = *(const short8*)&fa[nl][kt * 32 + quad * 8];
        short8 bu = Up[(kt * 16 + wave) * 64 + lane];
        P  = __builtin_amdgcn_mfma_f32_16x16x32_bf16(av, bu, P,  0, 0, 0);
        FU = __builtin_amdgcn_mfma_f32_16x16x32_bf16(af, bu, FU, 0, 0, 0);
    }
    __syncthreads();   // va/fa reads done before wu8 overwrites them

    // ---- stage WU fragments into LDS (linear, conflict-free)
#pragma unroll
    for (int i = 0; i < 8; i++)
        wu8[tid + i * 1024] = WUp[tid + i * 1024];
    // (covered by the first in-loop __syncthreads below)

    // ---- step recurrence in [16][256] space; P fp32 in regs.
    floatx4 A1 = {0.f, 0.f, 0.f, 0.f};   // sum G_j
    floatx4 Q2 = {0.f, 0.f, 0.f, 0.f};   // sum (steps-1-j) G_j
    for (int s = 0; s < steps; s++) {
        short (*pw)[264] = (s & 1) ? q2 : q1;   // double buffer
        float wgt = (float)(steps - 1 - s);
#pragma unroll
        for (int r = 0; r < 4; r++) {
            float g = P[r] * P[r];
            A1[r] += g;
            Q2[r] += wgt * g;
            pw[4 * quad + r][16 * wave + nl] = (short)f2bf(g);
        }
        __syncthreads();
        floatx4 acc = {0.f, 0.f, 0.f, 0.f};
#pragma unroll
        for (int kt = 0; kt < 8; kt++) {
            short8 a = *(const short8*)&pw[nl][kt * 32 + quad * 8];
            short8 b = wu8[(kt * 16 + wave) * 64 + lane];
            acc = __builtin_amdgcn_mfma_f32_16x16x32_bf16(a, b, acc, 0, 0, 0);
        }
#pragma unroll
        for (int r = 0; r < 4; r++)
            P[r] += DT * (FU[r] - acc[r]);
        // no barrier here: next iter writes the OTHER buffer; its barrier
        // guarantees all waves finished this iter's reads first.
    }
    __syncthreads();   // all reads of last pw done before q1/q2 overwrite

    // ---- write Q1 (=A1), Q2 as bf16 A-operands
#pragma unroll
    for (int r = 0; r < 4; r++) {
        q1[4 * quad + r][16 * wave + nl] = (short)f2bf(A1[r]);
        q2[4 * quad + r][16 * wave + nl] = (short)f2bf(Q2[r]);
    }
    __syncthreads();

    // ---- final GEMMs (share B): Y1 = Q1@W, Y2 = Q2@W ; wave nt = 4w..4w+3
    floatx4 y1[4], y2[4];
#pragma unroll
    for (int t = 0; t < 4; t++) {
        y1[t] = (floatx4){0.f, 0.f, 0.f, 0.f};
        y2[t] = (floatx4){0.f, 0.f, 0.f, 0.f};
    }
#pragma unroll 2
    for (int kt = 0; kt < 8; kt++) {
        short8 a1 = *(const short8*)&q1[nl][kt * 32 + quad * 8];
        short8 a2 = *(const short8*)&q2[nl][kt * 32 + quad * 8];
#pragma unroll
        for (int t = 0; t < 4; t++) {
            short8 b = Wp[(kt * 64 + 4 * wave + t) * 64 + lane];
            y1[t] = __builtin_amdgcn_mfma_f32_16x16x32_bf16(a1, b, y1[t], 0, 0, 0);
            y2[t] = __builtin_amdgcn_mfma_f32_16x16x32_bf16(a2, b, y2[t], 0, 0, 0);
        }
    }

    // ---- outputs: cx = x0 + s*dt*v0 + T*dt^2*f - dt^2*Y2
    //              cv = v0 + s*dt*f - dt*Y1
    const float sdt  = steps * DT;
    const float tdt2 = 0.5f * (float)(steps * (steps - 1)) * DT * DT;
    float (*stage)[1032] = (float(*)[1032])smem;   // wu8/va/fa dead
    const float4* x4 = (const float4*)x0;
    float4* out4 = (float4*)out;

    for (int sel = 0; sel < 2; sel++) {          // 0: cx, 1: cv
        for (int half = 0; half < 2; half++) {   // rows 0..7, 8..15
            __syncthreads();
            if ((quad >> 1) == half) {
#pragma unroll
                for (int t = 0; t < 4; t++) {
                    int col = 64 * wave + 16 * t + nl;
#pragma unroll
                    for (int r = 0; r < 4; r++) {
                        int lrow = (4 * quad + r) & 7;
                        stage[lrow][col] = sel ? (-DT * y1[t][r])
                                               : (-DT * DT * y2[t][r]);
                    }
                }
            }
            __syncthreads();
            // linear pass: coalesced float4 reads of x0/v0/f + staged term
            for (int i = tid; i < 2048; i += 1024) {
                int lrow = i >> 8, c4 = i & 255;
                long gi = (long)(row0 + half * 8 + lrow) * 256 + c4;
                float4 s = *(const float4*)&stage[lrow][c4 * 4];
                float4 vv = v04[gi];
                float4 ff = f44[gi];
                float4 o;
                if (sel == 0) {
                    float4 xx = x4[gi];
                    o.x = xx.x + sdt * vv.x + tdt2 * ff.x + s.x;
                    o.y = xx.y + sdt * vv.y + tdt2 * ff.y + s.y;
                    o.z = xx.z + sdt * vv.z + tdt2 * ff.z + s.z;
                    o.w = xx.w + sdt * vv.w + tdt2 * ff.w + s.w;
                    out4[gi] = o;
                } else {
                    o.x = vv.x + sdt * ff.x + s.x;
                    o.y = vv.y + sdt * ff.y + s.y;
                    o.z = vv.z + sdt * ff.z + s.z;
                    o.w = vv.w + sdt * ff.w + s.w;
                    out4[(long)BB * 256 + gi] = o;
                }
            }
        }
    }
}

extern "C" void kernel_launch(void* const* d_in, const int* in_sizes, int n_in,
                              void* d_out, int out_size, void* d_ws, size_t ws_size,
                              hipStream_t stream) {
    const float* x     = (const float*)d_in[0];
    const float* v     = (const float*)d_in[1];
    const float* force = (const float*)d_in[2];
    const float* U     = (const float*)d_in[3];
    const float* W     = (const float*)d_in[4];
    const int*   steps = (const int*)d_in[5];

    short* Up  = (short*)d_ws;                // 262144 shorts = 512 KB
    short* Wp  = Up + 262144;                 // 512 KB
    short* WUp = Wp + 262144;                 // 65536 shorts = 128 KB

    pack_kernel<<<192, 1024, 0, stream>>>(U, W, Up, Wp, WUp);
    euler_kernel<<<256, 1024, 0, stream>>>(x, v, force,
                                           (const short8*)Up, (const short8*)Wp,
                                           (const short8*)WUp,
                                           steps, (float*)d_out);
}

// Round 6
// 146.259 us; speedup vs baseline: 2.6827x; 1.2899x over previous
//
#include <hip/hip_runtime.h>

// EulerIntegrator: B=4096, D=1024, R=256, steps=8, dt=0.01
// R6 = R5 resubmit (prior bench died on container acquire, not kernel).
// R5: pack path rebuilt (was 60us, latency-bound at 9% occupancy).
//  - U/W pack: gather-reads + coalesced 8B writes, 2 threads/fragment-lane.
//  - WU = W@U: 256 blocks (1 row each) x 1024 thr, 4-way k-split + LDS
//    reduce; exact same fp32-accumulate + f2bf numerics as R4.
//  - all roles in one 384-block kernel, fully co-resident.
// euler: step math unchanged (R4-verified); epilogue simplified to one
// LDS stage (both outputs) + 1 barrier + fused linear pass.
// Recurrence: P <- P + dt*(FU - (P*P)@WU) in [B,256];
//   v_fin = v0 + s*dt*f - dt*(Q1@W), x_fin = x0 + s*dt*v0 + T*dt^2*f - dt^2*(Q2@W)

#define BB 4096
#define DD 1024
#define RR 256
#define DT 0.01f

typedef __attribute__((ext_vector_type(8))) short short8;   // 8 bf16 = 4 VGPRs
typedef __attribute__((ext_vector_type(4))) short short4v;  // 4 bf16 = 8B
typedef __attribute__((ext_vector_type(4))) float floatx4;  // MFMA acc

static __device__ inline unsigned short f2bf(float f) {
    union { float f; unsigned int u; } c; c.f = f;
    unsigned int u = c.u;
    u += 0x7fffu + ((u >> 16) & 1u);   // round-to-nearest-even
    return (unsigned short)(u >> 16);
}

// Fragment layout (B-operand, 16x16x32): frag (kt,nt), lane l, elem j holds
// M[kt*32 + (l>>4)*8 + j][nt*16 + (l&15)]; short index = frag*512 + l*8 + j.
//
// Blocks 0..63:    pack U  (32 kt x 16 nt)
// Blocks 64..127:  pack W  ( 8 kt x 64 nt)
// Blocks 128..383: WU row i = b-128; 4-way k-split fp32 dot + LDS reduce.
__global__ __launch_bounds__(1024)
void pack_kernel(const float* __restrict__ U, const float* __restrict__ W,
                 short* __restrict__ Up, short* __restrict__ Wp,
                 short* __restrict__ WUp) {
    __shared__ float red[4][256];
    const int b = blockIdx.x;
    const int tid = threadIdx.x;

    if (b < 128) {
        const bool isU = (b < 64);
        const float* M = isU ? U : W;
        short* P = isU ? Up : Wp;
        const int ld = isU ? RR : DD;
        int t = (isU ? b : b - 64) * 1024 + tid;   // 0..65535
        int S = t * 4;                              // short index of first elem
        int j0   = S & 7;                           // 0 or 4
        int lane = (S >> 3) & 63;
        int frag = S >> 9;                          // kt*NT + nt
        int nl = lane & 15, kq = lane >> 4;
        int kt, nt;
        if (isU) { kt = frag >> 4; nt = frag & 15; }
        else     { kt = frag >> 6; nt = frag & 63; }
        int k0 = kt * 32 + kq * 8 + j0;
        int n  = nt * 16 + nl;
        short4v o;
#pragma unroll
        for (int jj = 0; jj < 4; jj++)
            o[jj] = (short)f2bf(M[(long)(k0 + jj) * ld + n]);
        *(short4v*)(P + S) = o;                     // coalesced 8B write
    } else {
        // WU[i][j] = sum_k W[i][k]*U[k][j]; i = b-128; thread (kk,j).
        const int i  = b - 128;
        const int kk = tid >> 8;                    // 0..3
        const int j  = tid & 255;
        const float* wr = W + (long)i * DD + kk * 256;
        const float* uc = U + (long)(kk * 256) * RR + j;
        float a0 = 0.f, a1 = 0.f, a2 = 0.f, a3 = 0.f;
#pragma unroll 8
        for (int m = 0; m < 256; m += 4) {
            a0 += wr[m + 0] * uc[(m + 0) * RR];
            a1 += wr[m + 1] * uc[(m + 1) * RR];
            a2 += wr[m + 2] * uc[(m + 2) * RR];
            a3 += wr[m + 3] * uc[(m + 3) * RR];
        }
        red[kk][j] = (a0 + a1) + (a2 + a3);
        __syncthreads();
        if (tid < 256) {
            float acc = red[0][tid] + red[1][tid] + red[2][tid] + red[3][tid];
            int ktw = i >> 5, kqw = (i >> 3) & 3, jjw = i & 7;
            int ntw = tid >> 4, nlw = tid & 15;
            WUp[(((ktw * 16 + ntw) * 64) + kqw * 16 + nlw) * 8 + jjw] =
                (short)f2bf(acc);
        }
    }
}

__global__ __launch_bounds__(1024)
void euler_kernel(const float* __restrict__ x0,
                  const float* __restrict__ v0,
                  const float* __restrict__ force,
                  const short8* __restrict__ Up,
                  const short8* __restrict__ Wp,
                  const short8* __restrict__ WUp,
                  const int* __restrict__ steps_p,
                  float* __restrict__ out) {
    // LDS layout (shorts), total 73984 shorts = 147,968 B (1 block/CU):
    //   [0      .. 65535]  wu8: WU fragments (8192 short8) -- staged after init;
    //                      ALIASED during init: va [16][1032] at 0, fa at 16512;
    //                      ALIASED during epilogue: s1/s2 f32 [16][1024] each
    //                      (bytes [0,131072) -- ends exactly at q1, no overlap).
    //   [65536  .. 69759]  p2 buf0 [16][264] (steps dbuf / final Q1)
    //   [69760  .. 73983]  p2 buf1 [16][264] (steps dbuf / final Q2)
    __shared__ __align__(16) short smem[73984];

    const int tid  = threadIdx.x;
    const int wave = tid >> 6;          // 0..15
    const int lane = tid & 63;
    const int nl   = lane & 15;
    const int quad = lane >> 4;
    const int row0 = blockIdx.x * 16;
    const int steps = steps_p[0];

    short (*va)[1032] = (short(*)[1032])smem;
    short (*fa)[1032] = (short(*)[1032])(smem + 16512);
    short (*q1)[264]  = (short(*)[264])(smem + 65536);
    short (*q2)[264]  = (short(*)[264])(smem + 69760);
    short8* wu8 = (short8*)smem;

    // ---- stage v0, f as bf16 (coalesced float4 reads)
    const float4* v04 = (const float4*)v0;
    const float4* f44 = (const float4*)force;
#pragma unroll
    for (int i = 0; i < 4; i++) {
        int idx = tid + i * 1024;       // 0..4095
        int row = idx >> 8, c4 = idx & 255;
        long g = (long)(row0 + row) * 256 + c4;
        float4 vv = v04[g];
        float4 ff = f44[g];
        short4v sv, sf;
        sv[0] = (short)f2bf(vv.x); sv[1] = (short)f2bf(vv.y);
        sv[2] = (short)f2bf(vv.z); sv[3] = (short)f2bf(vv.w);
        sf[0] = (short)f2bf(ff.x); sf[1] = (short)f2bf(ff.y);
        sf[2] = (short)f2bf(ff.z); sf[3] = (short)f2bf(ff.w);
        *(short4v*)&va[row][c4 * 4] = sv;
        *(short4v*)&fa[row][c4 * 4] = sf;
    }
    __syncthreads();

    // ---- init GEMMs (share B): P = v0@U, FU = f@U ; wave's nt = wave
    floatx4 P  = {0.f, 0.f, 0.f, 0.f};
    floatx4 FU = {0.f, 0.f, 0.f, 0.f};
#pragma unroll 4
    for (int kt = 0; kt < 32; kt++) {
        short8 av = *(const short8*)&va[nl][kt * 32 + quad * 8];
        short8 af = *(const short8*)&fa[nl][kt * 32 + quad * 8];
        short8 bu = Up[(kt * 16 + wave) * 64 + lane];
        P  = __builtin_amdgcn_mfma_f32_16x16x32_bf16(av, bu, P,  0, 0, 0);
        FU = __builtin_amdgcn_mfma_f32_16x16x32_bf16(af, bu, FU, 0, 0, 0);
    }
    __syncthreads();   // va/fa reads done before wu8 overwrites them

    // ---- stage WU fragments into LDS (linear, conflict-free)
#pragma unroll
    for (int i = 0; i < 8; i++)
        wu8[tid + i * 1024] = WUp[tid + i * 1024];
    // (covered by the first in-loop __syncthreads below)

    // ---- step recurrence in [16][256] space; P fp32 in regs.
    floatx4 A1 = {0.f, 0.f, 0.f, 0.f};   // sum G_j
    floatx4 Q2 = {0.f, 0.f, 0.f, 0.f};   // sum (steps-1-j) G_j
    for (int s = 0; s < steps; s++) {
        short (*pw)[264] = (s & 1) ? q2 : q1;   // double buffer
        float wgt = (float)(steps - 1 - s);
#pragma unroll
        for (int r = 0; r < 4; r++) {
            float g = P[r] * P[r];
            A1[r] += g;
            Q2[r] += wgt * g;
            pw[4 * quad + r][16 * wave + nl] = (short)f2bf(g);
        }
        __syncthreads();
        floatx4 acc = {0.f, 0.f, 0.f, 0.f};
#pragma unroll
        for (int kt = 0; kt < 8; kt++) {
            short8 a = *(const short8*)&pw[nl][kt * 32 + quad * 8];
            short8 b = wu8[(kt * 16 + wave) * 64 + lane];
            acc = __builtin_amdgcn_mfma_f32_16x16x32_bf16(a, b, acc, 0, 0, 0);
        }
#pragma unroll
        for (int r = 0; r < 4; r++)
            P[r] += DT * (FU[r] - acc[r]);
        // no barrier: next iter writes the OTHER buffer; its barrier
        // guarantees all waves finished this iter's reads first.
    }
    __syncthreads();   // all reads of last pw done before q1/q2 overwrite

    // ---- write Q1 (=A1), Q2 as bf16 A-operands
#pragma unroll
    for (int r = 0; r < 4; r++) {
        q1[4 * quad + r][16 * wave + nl] = (short)f2bf(A1[r]);
        q2[4 * quad + r][16 * wave + nl] = (short)f2bf(Q2[r]);
    }
    __syncthreads();

    // ---- final GEMMs (share B): Y1 = Q1@W, Y2 = Q2@W ; wave nt = 4w..4w+3
    floatx4 y1[4], y2[4];
#pragma unroll
    for (int t = 0; t < 4; t++) {
        y1[t] = (floatx4){0.f, 0.f, 0.f, 0.f};
        y2[t] = (floatx4){0.f, 0.f, 0.f, 0.f};
    }
#pragma unroll 2
    for (int kt = 0; kt < 8; kt++) {
        short8 a1 = *(const short8*)&q1[nl][kt * 32 + quad * 8];
        short8 a2 = *(const short8*)&q2[nl][kt * 32 + quad * 8];
#pragma unroll
        for (int t = 0; t < 4; t++) {
            short8 b = Wp[(kt * 64 + 4 * wave + t) * 64 + lane];
            y1[t] = __builtin_amdgcn_mfma_f32_16x16x32_bf16(a1, b, y1[t], 0, 0, 0);
            y2[t] = __builtin_amdgcn_mfma_f32_16x16x32_bf16(a2, b, y2[t], 0, 0, 0);
        }
    }

    // ---- epilogue: stage BOTH GEMM terms in dead LDS (bytes [0,131072),
    // no overlap with q1/q2), one barrier, fused coalesced linear pass.
    //   cx = x0 + s*dt*v0 + T*dt^2*f - dt^2*Y2
    //   cv = v0 + s*dt*f - dt*Y1
    float (*s1)[1024] = (float(*)[1024])smem;            // -dt*Y1
    float (*s2)[1024] = (float(*)[1024])(smem + 32768);  // -dt^2*Y2
#pragma unroll
    for (int t = 0; t < 4; t++) {
        int col = 64 * wave + 16 * t + nl;
#pragma unroll
        for (int r = 0; r < 4; r++) {
            int row = 4 * quad + r;
            s1[row][col] = -DT * y1[t][r];
            s2[row][col] = -DT * DT * y2[t][r];
        }
    }
    __syncthreads();

    const float sdt  = steps * DT;
    const float tdt2 = 0.5f * (float)(steps * (steps - 1)) * DT * DT;
    const float4* x4 = (const float4*)x0;
    float4* out4 = (float4*)out;
#pragma unroll
    for (int p = 0; p < 4; p++) {
        int idx = tid + p * 1024;       // 0..4095
        int row = idx >> 8, c4 = idx & 255;
        long gi = (long)(row0 + row) * 256 + c4;
        float4 vv = v04[gi];
        float4 ff = f44[gi];
        float4 xx = x4[gi];
        float4 t1 = *(const float4*)&s1[row][c4 * 4];
        float4 t2 = *(const float4*)&s2[row][c4 * 4];
        float4 ox, ov;
        ox.x = xx.x + sdt * vv.x + tdt2 * ff.x + t2.x;
        ox.y = xx.y + sdt * vv.y + tdt2 * ff.y + t2.y;
        ox.z = xx.z + sdt * vv.z + tdt2 * ff.z + t2.z;
        ox.w = xx.w + sdt * vv.w + tdt2 * ff.w + t2.w;
        ov.x = vv.x + sdt * ff.x + t1.x;
        ov.y = vv.y + sdt * ff.y + t1.y;
        ov.z = vv.z + sdt * ff.z + t1.z;
        ov.w = vv.w + sdt * ff.w + t1.w;
        out4[gi] = ox;
        out4[(long)BB * 256 + gi] = ov;
    }
}

extern "C" void kernel_launch(void* const* d_in, const int* in_sizes, int n_in,
                              void* d_out, int out_size, void* d_ws, size_t ws_size,
                              hipStream_t stream) {
    const float* x     = (const float*)d_in[0];
    const float* v     = (const float*)d_in[1];
    const float* force = (const float*)d_in[2];
    const float* U     = (const float*)d_in[3];
    const float* W     = (const float*)d_in[4];
    const int*   steps = (const int*)d_in[5];

    short* Up  = (short*)d_ws;                // 262144 shorts = 512 KB
    short* Wp  = Up + 262144;                 // 512 KB
    short* WUp = Wp + 262144;                 // 65536 shorts = 128 KB

    pack_kernel<<<384, 1024, 0, stream>>>(U, W, Up, Wp, WUp);
    euler_kernel<<<256, 1024, 0, stream>>>(x, v, force,
                                           (const short8*)Up, (const short8*)Wp,
                                           (const short8*)WUp,
                                           steps, (float*)d_out);
}